// Round 3
// baseline (434.669 us; speedup 1.0000x reference)
//
#include <hip/hip_runtime.h>
#include <cstdint>

namespace {

constexpr int W = 256;
constexpr int ITERS = 10;
constexpr int FP_STR = 260;   // fpart row stride (floats)

// R10: mirrored geometry. 1024 thr / 16 waves, 64-VGPR pin respected
// (R7/R8/R9 falsified every knob; 16-wave => 64 VGPR, hard).
// Wave w owns rows [16w,16w+16); lane owns cols [4l,4l+4). E split:
// rows 0..7 in regs (32 fl), rows 8..15 in thread-private XOR-swizzled LDS
// chunks (32 fl, 128 KB). Row reduction (-> eu) is an in-wave butterfly:
// eu stays in REGISTERS, no LDS broadcast, no barrier. Col reduction
// (-> ev) keeps fpart + 256-thread finalize with a permuted column slot
// (slot = lane + 64*s) so every access is lane-consecutive/conflict-free.
// 2 barriers/iter (was 4); finale argmax/window is wave-private (row i
// lives entirely in wave i>>4) so the packed-u64 LDS argmax disappears.
__global__ __launch_bounds__(1024)
void sinkhorn_disp_kernel(
    const float* __restrict__ attn,
    const float* __restrict__ phi_p,
    float* __restrict__ out,
    int nh)
{
  __shared__ __align__(16) float E_lds[1024 * 32];   // 128 KB, rows 8..15
  __shared__ __align__(16) float fpart[16][FP_STR];  // 16.6 KB col partials
  __shared__ __align__(16) float ev_lds[W + 4];      // permuted ev slots
  __shared__ __align__(16) float seup[2][16];        // per-wave sum(eu), dbuf
  __shared__ float win[W][3];

  const int tid  = threadIdx.x;
  const int lane = tid & 63;
  const int wid  = tid >> 6;
  const int bid  = blockIdx.x;
  const int sw   = tid & 7;                  // chunk swizzle key
  float* myE = &E_lds[tid * 32];
  // chunk c (0..7) <-> tile row 8+c, this lane's 4 cols
  #define RDCH(c) (*(const float4*)&myE[4 * ((c) ^ sw)])

  const float ephi  = __expf(phi_p[0]);
  const float inv2w = 1.0f / (2.0f * W);

  // ---- load + exp: rows 0..7 -> regs, rows 8..15 -> swizzled LDS ----
  float Er[8][4];
  {
    const float* src = attn + (size_t)bid * (W * W)
                     + (size_t)(wid * 16) * W + lane * 4;
    #pragma unroll
    for (int r = 0; r < 8; ++r) {          // 64 lanes x 16B = 1 KB coalesced
      float4 x = *(const float4*)(src + r * W);
      Er[r][0] = __expf(x.x); Er[r][1] = __expf(x.y);
      Er[r][2] = __expf(x.z); Er[r][3] = __expf(x.w);
    }
    #pragma unroll
    for (int c = 0; c < 8; ++c) {
      float4 x = *(const float4*)(src + (8 + c) * W);
      *(float4*)&myE[4 * (c ^ sw)] =
          make_float4(__expf(x.x), __expf(x.y), __expf(x.z), __expf(x.w));
    }
  }
  float eul[16];
  #pragma unroll
  for (int r = 0; r < 16; ++r) eul[r] = 1.0f;   // u0 = 0
  float euW = 1.0f;
  if (tid < 16) seup[1][tid] = 16.0f;           // sum of 16 init eu per wave

  float evc0 = 0.f, evc1 = 0.f, evc2 = 0.f, evc3 = 0.f;  // live out of loop
  float evW  = 0.f;

  for (int it = 0; it < ITERS; ++it) {
    // ---- col partials over this wave's 16 rows (cols 4l..4l+4) ----
    {
      float cp0 = 0.f, cp1 = 0.f, cp2 = 0.f, cp3 = 0.f;
      #pragma unroll
      for (int r = 0; r < 8; ++r) {
        float u = eul[r];
        cp0 = __builtin_fmaf(Er[r][0], u, cp0);
        cp1 = __builtin_fmaf(Er[r][1], u, cp1);
        cp2 = __builtin_fmaf(Er[r][2], u, cp2);
        cp3 = __builtin_fmaf(Er[r][3], u, cp3);
      }
      #pragma unroll
      for (int c = 0; c < 8; ++c) {
        float4 e = RDCH(c);
        float u = eul[8 + c];
        cp0 = __builtin_fmaf(e.x, u, cp0);
        cp1 = __builtin_fmaf(e.y, u, cp1);
        cp2 = __builtin_fmaf(e.z, u, cp2);
        cp3 = __builtin_fmaf(e.w, u, cp3);
      }
      // permuted slots: col 4l+s -> slot l+64s; lane-consecutive writes
      fpart[wid][lane      ] = cp0;
      fpart[wid][lane +  64] = cp1;
      fpart[wid][lane + 128] = cp2;
      fpart[wid][lane + 192] = cp3;
    }
    __syncthreads();                       // barrier 1
    // ---- col finalize: thread t owns slot t (col 4*(t&63)+(t>>6)) ----
    if (tid < W) {
      float s = 0.f;
      #pragma unroll
      for (int w = 0; w < 16; ++w) s += fpart[w][tid];
      ev_lds[tid] = inv2w / (s + ephi * euW);
    }
    __syncthreads();                       // barrier 2
    // ---- in-wave row pass: ev -> eu entirely in registers ----
    evc0 = ev_lds[lane      ];
    evc1 = ev_lds[lane +  64];
    evc2 = ev_lds[lane + 128];
    evc3 = ev_lds[lane + 192];
    float Seu = euW;                       // Seu of the eu used above
    {
      const float4* sp = (const float4*)&seup[(it + 1) & 1][0];
      float4 a = sp[0], b = sp[1], c = sp[2], d = sp[3];
      Seu += a.x + a.y + a.z + a.w + b.x + b.y + b.z + b.w
           + c.x + c.y + c.z + c.w + d.x + d.y + d.z + d.w;
    }
    evW = 0.5f / (ephi * Seu);
    float eAdd = ephi * evW;
    float sevLocal = evc0 + evc1 + evc2 + evc3;
    float rs[16];
    #pragma unroll
    for (int r = 0; r < 8; ++r)
      rs[r] = Er[r][0] * evc0 + Er[r][1] * evc1
            + Er[r][2] * evc2 + Er[r][3] * evc3;
    #pragma unroll
    for (int c = 0; c < 8; ++c) {
      float4 e = RDCH(c);
      rs[8 + c] = e.x * evc0 + e.y * evc1 + e.z * evc2 + e.w * evc3;
    }
    #pragma unroll
    for (int off = 1; off < 64; off <<= 1) {
      #pragma unroll
      for (int r = 0; r < 16; ++r) rs[r] += __shfl_xor(rs[r], off, 64);
    }
    #pragma unroll
    for (int r = 0; r < 16; ++r) eul[r] = inv2w / (rs[r] + eAdd);
    #pragma unroll
    for (int off = 1; off < 64; off <<= 1)
      sevLocal += __shfl_xor(sevLocal, off, 64);
    euW = 0.5f / (ephi * (sevLocal + evW));
    if (lane == 0) {
      float s = 0.f;
      #pragma unroll
      for (int r = 0; r < 16; ++r) s += eul[r];
      seup[it & 1][wid] = s;
    }
  }

  // ---- finale: per-wave argmax + 3-tap window (all wave-private) ----
  if (lane < 16) {
    win[wid * 16 + lane][0] = 0.f;
    win[wid * 16 + lane][1] = 0.f;
    win[wid * 16 + lane][2] = 0.f;
  }
  int jm_keep = 0;
  #pragma unroll
  for (int r = 0; r < 16; ++r) {
    float e0, e1, e2, e3;
    if (r < 8) {
      e0 = Er[r < 8 ? r : 0][0]; e1 = Er[r < 8 ? r : 0][1];
      e2 = Er[r < 8 ? r : 0][2]; e3 = Er[r < 8 ? r : 0][3];
    } else {
      float4 e = RDCH(r - 8);
      e0 = e.x; e1 = e.y; e2 = e.z; e3 = e.w;
    }
    float v0 = e0 * evc0, v1 = e1 * evc1, v2 = e2 * evc2, v3 = e3 * evc3;
    float m = v0; int mj = lane * 4;
    if (v1 > m) { m = v1; mj = lane * 4 + 1; }   // strict >: first max
    if (v2 > m) { m = v2; mj = lane * 4 + 2; }
    if (v3 > m) { m = v3; mj = lane * 4 + 3; }
    // pack (value, first-index-wins); values > 0 so float bits order-preserve
    unsigned long long best =
        (((unsigned long long)__float_as_uint(m)) << 32) |
        (unsigned)(65535 - mj);
    #pragma unroll
    for (int off = 1; off < 64; off <<= 1) {
      unsigned long long o = __shfl_xor(best, off, 64);
      best = (o > best) ? o : best;
    }
    int jm = 65535 - (int)(best & 0xffffffffull);
    if (lane == r) jm_keep = jm;
    // window scatter: unique owner of col j writes P[i][j]
    const int i = wid * 16 + r;
    float us = eul[r] * (2.0f * W);
    { int k = 4 * lane     - (jm - 1); if (k >= 0 && k < 3) win[i][k] = v0 * us; }
    { int k = 4 * lane + 1 - (jm - 1); if (k >= 0 && k < 3) win[i][k] = v1 * us; }
    { int k = 4 * lane + 2 - (jm - 1); if (k >= 0 && k < 3) win[i][k] = v2 * us; }
    { int k = 4 * lane + 3 - (jm - 1); if (k >= 0 && k < 3) win[i][k] = v3 * us; }
  }
  __syncthreads();   // one-time: make win visible (paranoia; traffic is in-wave)
  if (lane < 16) {
    const int i  = wid * 16 + lane;
    const int jm = jm_keep;
    float w0 = win[i][0], w1 = win[i][1], w2 = win[i][2];
    float norm0 = w0 + w1 + w2;
    float norm  = (norm0 < 0.1f) ? 1.0f : norm0;
    float p0 = fmaxf((float)(i - (jm - 1)), 0.0f);
    float p1 = fmaxf((float)(i - jm),       0.0f);
    float p2 = fmaxf((float)(i - (jm + 1)), 0.0f);
    float disp = (w0 / norm) * p0 + (w1 / norm) * p1 + (w2 / norm) * p2;
    float occ  = 1.0f - norm;
    out[(size_t)bid * W + i] = disp;
    out[(size_t)nh * W + (size_t)bid * W + i] = occ;
  }
  #undef RDCH
}

} // namespace

extern "C" void kernel_launch(void* const* d_in, const int* in_sizes, int n_in,
                              void* d_out, int out_size, void* d_ws, size_t ws_size,
                              hipStream_t stream) {
  (void)n_in; (void)d_ws; (void)ws_size; (void)out_size;
  const float* attn = (const float*)d_in[0];
  const float* phi  = (const float*)d_in[1];
  float* out = (float*)d_out;
  const int nh = in_sizes[0] / (W * W);   // 4*120 = 480 matrices
  sinkhorn_disp_kernel<<<dim3(nh), dim3(1024), 0, stream>>>(attn, phi, out, nh);
}

// Round 4
// 241.088 us; speedup vs baseline: 1.8029x; 1.8029x over previous
//
#include <hip/hip_runtime.h>
#include <cstdint>

namespace {

constexpr int W = 256;
constexpr int ITERS = 10;
constexpr int PSTR = 260;   // fpart row stride (floats)

// R11: R7 storage (32-reg E + 32-swizzled-LDS E, 64-VGPR pin respected),
// but: eu in registers (row reduce = width-32 allreduce: 2 DPP adds on the
// VALU pipe + 3 ds_swizzle adds), 2 barriers/iter instead of 4, fpart/ev
// XOR-chunk-swizzled (conflict-free b128 writes + b32 reads), finalize
// spread over 512 threads, v_rcp for Sinkhorn divides, finale without
// win/jmax LDS (window via 2-value allreduce).
__device__ __forceinline__ float dpp_add_xor1(float x) {
  int y = __builtin_amdgcn_mov_dpp(__float_as_int(x), 0xB1, 0xF, 0xF, true);
  return x + __int_as_float(y);
}
__device__ __forceinline__ float dpp_add_xor2(float x) {
  int y = __builtin_amdgcn_mov_dpp(__float_as_int(x), 0x4E, 0xF, 0xF, true);
  return x + __int_as_float(y);
}
template <int PAT>
__device__ __forceinline__ float swz_add(float x) {
  return x + __int_as_float(__builtin_amdgcn_ds_swizzle(__float_as_int(x), PAT));
}
__device__ __forceinline__ float allred32(float x) {  // sum over 32-lane group
  x = dpp_add_xor1(x);
  x = dpp_add_xor2(x);
  x = swz_add<0x101F>(x);   // xor 4
  x = swz_add<0x201F>(x);   // xor 8
  x = swz_add<0x401F>(x);   // xor 16
  return x;
}
__device__ __forceinline__ float rcpf(float x) {
  float r;
  asm("v_rcp_f32 %0, %1" : "=v"(r) : "v"(x));
  return r;
}

__global__ __launch_bounds__(1024)
void sinkhorn_disp_kernel(
    const float* __restrict__ attn,
    const float* __restrict__ phi_p,
    float* __restrict__ out,
    int nh)
{
  __shared__ __align__(16) float E_lds[1024 * 32];   // 128 KB, rows 4..7
  __shared__ __align__(16) float fpart[16][PSTR];    // 16.6 KB, swizzled cols
  __shared__ __align__(16) float ev_l[W];            // swizzled ev
  __shared__ __align__(16) float seup[32];           // per-half-wave sum(eu)
  __shared__ float evW_s;

  const int tid = threadIdx.x;
  const int tc  = tid & 31;                  // col group: cols [8tc, 8tc+8)
  const int tr  = tid >> 5;                  // row group: rows [8tr, 8tr+8)
  const int bid = blockIdx.x;
  const int sw  = tid & 7;                   // E-chunk swizzle key
  float* myE = &E_lds[tid * 32];
  // chunk c (0..7) <-> tile row 4+(c>>1), cols (c&1)*4 .. +3
  #define RDCH(c) (*(const float4*)&myE[4 * ((c) ^ sw)])

  const float ephi  = __expf(phi_p[0]);
  const float inv2w = 1.0f / (2.0f * W);

  // swizzled float offset of this thread's first 16B chunk of a 256-f row:
  // chunk c = 2tc+h -> c' = c ^ ((tc>>2)&7); second chunk = ch0 ^ (4 floats)
  const int ch0 = 4 * ((2 * tc) ^ ((tc >> 2) & 7));

  // ---- load + exp: rows 0..3 -> registers, rows 4..7 -> swizzled LDS ----
  float Er[4][8];
  {
    const float* src = attn + (size_t)bid * (W * W) + (size_t)(tr * 8) * W + tc * 8;
    #pragma unroll
    for (int a = 0; a < 4; ++a) {
      float4 x0 = *(const float4*)(src + a * W);
      float4 x1 = *(const float4*)(src + a * W + 4);
      Er[a][0] = __expf(x0.x); Er[a][1] = __expf(x0.y);
      Er[a][2] = __expf(x0.z); Er[a][3] = __expf(x0.w);
      Er[a][4] = __expf(x1.x); Er[a][5] = __expf(x1.y);
      Er[a][6] = __expf(x1.z); Er[a][7] = __expf(x1.w);
    }
    #pragma unroll
    for (int ap = 0; ap < 4; ++ap) {
      float4 x0 = *(const float4*)(src + (4 + ap) * W);
      float4 x1 = *(const float4*)(src + (4 + ap) * W + 4);
      *(float4*)&myE[4 * ((2 * ap)     ^ sw)] =
          make_float4(__expf(x0.x), __expf(x0.y), __expf(x0.z), __expf(x0.w));
      *(float4*)&myE[4 * ((2 * ap + 1) ^ sw)] =
          make_float4(__expf(x1.x), __expf(x1.y), __expf(x1.z), __expf(x1.w));
    }
  }
  // E_lds chunks are thread-private (myE); fpart/seup/ev_l are produced
  // later behind barriers -> no initial __syncthreads needed.

  float eul[8];
  #pragma unroll
  for (int a = 0; a < 8; ++a) eul[a] = 1.0f;   // u0 = 0 -> eu = 1
  float euW = 1.0f;

  for (int it = 0; it < ITERS; ++it) {
    // ---- col pass: cp[b] = sum_a E[8tr+a][8tc+b] * eu[8tr+a] ----
    {
      float cp[8];
      #pragma unroll
      for (int b = 0; b < 8; ++b) cp[b] = 0.0f;
      #pragma unroll
      for (int a = 0; a < 4; ++a) {
        #pragma unroll
        for (int b = 0; b < 8; ++b)
          cp[b] = __builtin_fmaf(Er[a][b], eul[a], cp[b]);
      }
      #pragma unroll
      for (int ap = 0; ap < 4; ++ap) {
        float4 e0 = RDCH(2 * ap), e1 = RDCH(2 * ap + 1);
        float ua = eul[4 + ap];
        cp[0] = __builtin_fmaf(e0.x, ua, cp[0]);
        cp[1] = __builtin_fmaf(e0.y, ua, cp[1]);
        cp[2] = __builtin_fmaf(e0.z, ua, cp[2]);
        cp[3] = __builtin_fmaf(e0.w, ua, cp[3]);
        cp[4] = __builtin_fmaf(e1.x, ua, cp[4]);
        cp[5] = __builtin_fmaf(e1.y, ua, cp[5]);
        cp[6] = __builtin_fmaf(e1.z, ua, cp[6]);
        cp[7] = __builtin_fmaf(e1.w, ua, cp[7]);
      }
      // combine tr-parity pair (lane <-> lane^32: same tc, tr^1)
      #pragma unroll
      for (int b = 0; b < 8; ++b) cp[b] += __shfl_xor(cp[b], 32, 64);
      if (!(tr & 1)) {   // conflict-free b128 writes (chunk XOR swizzle)
        *(float4*)&fpart[tr >> 1][ch0    ] = make_float4(cp[0], cp[1], cp[2], cp[3]);
        *(float4*)&fpart[tr >> 1][ch0 ^ 4] = make_float4(cp[4], cp[5], cp[6], cp[7]);
      }
      if (tc == 0)
        seup[tr] = ((eul[0] + eul[1]) + (eul[2] + eul[3]))
                 + ((eul[4] + eul[5]) + (eul[6] + eul[7]));
    }
    __syncthreads();                       // barrier 1
    // ---- finalize ev: 512 threads, pair (2k,2k+1) splits the 16 groups ----
    if (tid < 2 * W) {
      const int j  = tid >> 1;
      const int fj = ((((j >> 2) ^ ((j >> 5) & 7)) << 2) | (j & 3));
      const int g0 = (tid & 1) * 8;
      float s = 0.0f;
      #pragma unroll
      for (int g = 0; g < 8; ++g) s += fpart[g0 + g][fj];
      s = dpp_add_xor1(s);                 // pair-combine (same j)
      if (!(tid & 1)) ev_l[fj] = inv2w * rcpf(s + ephi * euW);
    } else if ((tid >> 6) == 8) {          // wave 8: Seu reduce -> evW
      float s = allred32(seup[tid & 31]);
      if (tid == 512) evW_s = 0.5f * rcpf(ephi * (s + euW));
    }
    __syncthreads();                       // barrier 2
    // ---- row pass: in-register u-update via width-32 allreduce ----
    {
      const float evW = evW_s;
      float4 v0 = *(const float4*)&ev_l[ch0];
      float4 v1 = *(const float4*)&ev_l[ch0 ^ 4];
      float vl[8] = {v0.x, v0.y, v0.z, v0.w, v1.x, v1.y, v1.z, v1.w};
      float rp[8];
      #pragma unroll
      for (int a = 0; a < 4; ++a) {
        float s = 0.0f;
        #pragma unroll
        for (int b = 0; b < 8; ++b)
          s = __builtin_fmaf(Er[a][b], vl[b], s);
        rp[a] = s;
      }
      #pragma unroll
      for (int ap = 0; ap < 4; ++ap) {
        float4 e0 = RDCH(2 * ap), e1 = RDCH(2 * ap + 1);
        rp[4 + ap] = e0.x * vl[0] + e0.y * vl[1] + e0.z * vl[2] + e0.w * vl[3]
                   + e1.x * vl[4] + e1.y * vl[5] + e1.z * vl[6] + e1.w * vl[7];
      }
      float sev = ((vl[0] + vl[1]) + (vl[2] + vl[3]))
                + ((vl[4] + vl[5]) + (vl[6] + vl[7]));
      #pragma unroll
      for (int a = 0; a < 8; ++a) rp[a] = allred32(rp[a]);
      sev = allred32(sev);
      const float eAdd = ephi * evW;
      #pragma unroll
      for (int a = 0; a < 8; ++a) eul[a] = inv2w * rcpf(rp[a] + eAdd);
      euW = 0.5f * rcpf(ephi * (sev + evW));
    }
  }

  // ---- finale: per-row argmax + 3-tap window, all in-wave ----
  float vl[8];
  {
    float4 v0 = *(const float4*)&ev_l[ch0];
    float4 v1 = *(const float4*)&ev_l[ch0 ^ 4];
    vl[0] = v0.x; vl[1] = v0.y; vl[2] = v0.z; vl[3] = v0.w;
    vl[4] = v1.x; vl[5] = v1.y; vl[6] = v1.z; vl[7] = v1.w;
  }
  float res_disp = 0.0f, res_occ = 0.0f;
  #pragma unroll
  for (int a = 0; a < 8; ++a) {
    float v[8];
    if (a < 4) {
      #pragma unroll
      for (int b = 0; b < 8; ++b) v[b] = Er[a < 4 ? a : 0][b] * vl[b];
    } else {
      float4 e0 = RDCH(2 * (a - 4)), e1 = RDCH(2 * (a - 4) + 1);
      v[0] = e0.x * vl[0]; v[1] = e0.y * vl[1];
      v[2] = e0.z * vl[2]; v[3] = e0.w * vl[3];
      v[4] = e1.x * vl[4]; v[5] = e1.y * vl[5];
      v[6] = e1.z * vl[6]; v[7] = e1.w * vl[7];
    }
    float m = v[0]; int mj = tc * 8;
    #pragma unroll
    for (int b = 1; b < 8; ++b) {
      if (v[b] > m) { m = v[b]; mj = tc * 8 + b; }   // strict >: first max
    }
    // pack (value, first-index-wins); values > 0 so float bits order-preserve
    unsigned long long best =
        (((unsigned long long)__float_as_uint(m)) << 32) |
        (unsigned)(65535 - mj);
    #pragma unroll
    for (int off = 16; off > 0; off >>= 1) {
      unsigned long long o = __shfl_xor(best, off, 32);
      if (o > best) best = o;
    }
    const int jm = 65535 - (int)(best & 0xffffffffull);
    const int i  = tr * 8 + a;
    const float us = eul[a] * (2.0f * W);
    float num = 0.0f, den = 0.0f;
    #pragma unroll
    for (int b = 0; b < 8; ++b) {
      int j = tc * 8 + b;
      if (j >= jm - 1 && j <= jm + 1) {
        float w = v[b] * us;
        den += w;
        num += w * fmaxf((float)(i - j), 0.0f);
      }
    }
    den = allred32(den);
    num = allred32(num);
    if (tc == a) {                         // lane a keeps row a's result
      float norm = (den < 0.1f) ? 1.0f : den;
      res_disp = num / norm;
      res_occ  = 1.0f - norm;
    }
  }
  if (tc < 8) {
    const int i = tr * 8 + tc;
    out[(size_t)bid * W + i] = res_disp;
    out[(size_t)nh * W + (size_t)bid * W + i] = res_occ;
  }
  #undef RDCH
}

} // namespace

extern "C" void kernel_launch(void* const* d_in, const int* in_sizes, int n_in,
                              void* d_out, int out_size, void* d_ws, size_t ws_size,
                              hipStream_t stream) {
  (void)n_in; (void)d_ws; (void)ws_size; (void)out_size;
  const float* attn = (const float*)d_in[0];
  const float* phi  = (const float*)d_in[1];
  float* out = (float*)d_out;
  const int nh = in_sizes[0] / (W * W);   // 4*120 = 480 matrices
  sinkhorn_disp_kernel<<<dim3(nh), dim3(1024), 0, stream>>>(attn, phi, out, nh);
}

// Round 5
// 235.844 us; speedup vs baseline: 1.8430x; 1.0222x over previous
//
#include <hip/hip_runtime.h>
#include <cstdint>

namespace {

constexpr int W = 256;
constexpr int ITERS = 10;
constexpr int PSTR = 260;   // fpart row stride (floats)

// R12 = R11 + three additive changes:
//  (1) E split shifted: rows 0..4 in regs (40 fl, uses the 12-reg headroom
//      R11 exposed at VGPR=52), rows 5..7 in LDS (6 chunks) -> E ds_read
//      traffic -25%. R11 analysis: E-chunk lane stride = 128B = 32 banks,
//      so the b128 reads are at the LDS bandwidth floor (8 cyc/wave-instr,
//      counted as "conflicts") -- only reading LESS helps.
//  (2) L3 prefetch: blocks 0..(nh-257) touch 1 float per 64B line of
//      matrix bid+256 during iters 2..5 (4096 lines / 1024 thr = 4 loads),
//      hiding round-2's ~10us HBM load burst under round-1 compute.
//  (3) ephi forced to SGPR (readfirstlane) to free a VGPR.
__device__ __forceinline__ float dpp_add_xor1(float x) {
  int y = __builtin_amdgcn_mov_dpp(__float_as_int(x), 0xB1, 0xF, 0xF, true);
  return x + __int_as_float(y);
}
__device__ __forceinline__ float dpp_add_xor2(float x) {
  int y = __builtin_amdgcn_mov_dpp(__float_as_int(x), 0x4E, 0xF, 0xF, true);
  return x + __int_as_float(y);
}
template <int PAT>
__device__ __forceinline__ float swz_add(float x) {
  return x + __int_as_float(__builtin_amdgcn_ds_swizzle(__float_as_int(x), PAT));
}
__device__ __forceinline__ float allred32(float x) {  // sum over 32-lane group
  x = dpp_add_xor1(x);
  x = dpp_add_xor2(x);
  x = swz_add<0x101F>(x);   // xor 4
  x = swz_add<0x201F>(x);   // xor 8
  x = swz_add<0x401F>(x);   // xor 16
  return x;
}
__device__ __forceinline__ float rcpf(float x) {
  float r;
  asm("v_rcp_f32 %0, %1" : "=v"(r) : "v"(x));
  return r;
}

__global__ __launch_bounds__(1024)
void sinkhorn_disp_kernel(
    const float* __restrict__ attn,
    const float* __restrict__ phi_p,
    float* __restrict__ out,
    int nh)
{
  __shared__ __align__(16) float E_lds[1024 * 32];   // rows 5..7 (6/8 slots)
  __shared__ __align__(16) float fpart[16][PSTR];    // 16.6 KB, swizzled cols
  __shared__ __align__(16) float ev_l[W];            // swizzled ev
  __shared__ __align__(16) float seup[32];           // per-half-wave sum(eu)
  __shared__ float evW_s;

  const int tid = threadIdx.x;
  const int tc  = tid & 31;                  // col group: cols [8tc, 8tc+8)
  const int tr  = tid >> 5;                  // row group: rows [8tr, 8tr+8)
  const int bid = blockIdx.x;
  const int sw  = tid & 7;                   // E-chunk swizzle key
  float* myE = &E_lds[tid * 32];
  // chunk c (2..7) <-> tile row 4+(c>>1) (i.e. rows 5..7), col half c&1
  #define RDCH(c) (*(const float4*)&myE[4 * ((c) ^ sw)])

  const float ephi  = __int_as_float(
      __builtin_amdgcn_readfirstlane(__float_as_int(__expf(phi_p[0]))));
  const float inv2w = 1.0f / (2.0f * W);

  // swizzled float offset of this thread's first 16B chunk of a 256-f row:
  // chunk c = 2tc+h -> c' = c ^ ((tc>>2)&7); second chunk = ch0 ^ (4 floats)
  const int ch0 = 4 * ((2 * tc) ^ ((tc >> 2) & 7));

  // ---- load + exp: rows 0..4 -> registers, rows 5..7 -> swizzled LDS ----
  float Er[5][8];
  {
    const float* src = attn + (size_t)bid * (W * W) + (size_t)(tr * 8) * W + tc * 8;
    #pragma unroll
    for (int a = 0; a < 5; ++a) {
      float4 x0 = *(const float4*)(src + a * W);
      float4 x1 = *(const float4*)(src + a * W + 4);
      Er[a][0] = __expf(x0.x); Er[a][1] = __expf(x0.y);
      Er[a][2] = __expf(x0.z); Er[a][3] = __expf(x0.w);
      Er[a][4] = __expf(x1.x); Er[a][5] = __expf(x1.y);
      Er[a][6] = __expf(x1.z); Er[a][7] = __expf(x1.w);
    }
    #pragma unroll
    for (int r = 0; r < 3; ++r) {            // rows 5..7 -> chunks 2+2r, 3+2r
      float4 x0 = *(const float4*)(src + (5 + r) * W);
      float4 x1 = *(const float4*)(src + (5 + r) * W + 4);
      *(float4*)&myE[4 * ((2 + 2 * r) ^ sw)] =
          make_float4(__expf(x0.x), __expf(x0.y), __expf(x0.z), __expf(x0.w));
      *(float4*)&myE[4 * ((3 + 2 * r) ^ sw)] =
          make_float4(__expf(x1.x), __expf(x1.y), __expf(x1.z), __expf(x1.w));
    }
  }

  float eul[8];
  #pragma unroll
  for (int a = 0; a < 8; ++a) eul[a] = 1.0f;   // u0 = 0 -> eu = 1
  float euW = 1.0f;

  for (int it = 0; it < ITERS; ++it) {
    // ---- L3 prefetch of matrix bid+256 (1 line/thread, iters 2..5) ----
    if (it >= 2 && it <= 5 && bid + 256 < nh) {
      const float* pf = attn + (size_t)(bid + 256) * (W * W)
                      + ((size_t)(it - 2) * 1024 + tid) * 16;   // 64B lines
      float x = *pf;
      asm volatile("" :: "v"(x));            // keep the load alive
    }
    // ---- col pass: cp[b] = sum_a E[8tr+a][8tc+b] * eu[8tr+a] ----
    {
      float cp[8];
      #pragma unroll
      for (int b = 0; b < 8; ++b) cp[b] = 0.0f;
      #pragma unroll
      for (int a = 0; a < 5; ++a) {
        #pragma unroll
        for (int b = 0; b < 8; ++b)
          cp[b] = __builtin_fmaf(Er[a][b], eul[a], cp[b]);
      }
      #pragma unroll
      for (int r = 0; r < 3; ++r) {
        float4 e0 = RDCH(2 + 2 * r), e1 = RDCH(3 + 2 * r);
        float ua = eul[5 + r];
        cp[0] = __builtin_fmaf(e0.x, ua, cp[0]);
        cp[1] = __builtin_fmaf(e0.y, ua, cp[1]);
        cp[2] = __builtin_fmaf(e0.z, ua, cp[2]);
        cp[3] = __builtin_fmaf(e0.w, ua, cp[3]);
        cp[4] = __builtin_fmaf(e1.x, ua, cp[4]);
        cp[5] = __builtin_fmaf(e1.y, ua, cp[5]);
        cp[6] = __builtin_fmaf(e1.z, ua, cp[6]);
        cp[7] = __builtin_fmaf(e1.w, ua, cp[7]);
      }
      // combine tr-parity pair (lane <-> lane^32: same tc, tr^1)
      #pragma unroll
      for (int b = 0; b < 8; ++b) cp[b] += __shfl_xor(cp[b], 32, 64);
      if (!(tr & 1)) {   // conflict-free b128 writes (chunk XOR swizzle)
        *(float4*)&fpart[tr >> 1][ch0    ] = make_float4(cp[0], cp[1], cp[2], cp[3]);
        *(float4*)&fpart[tr >> 1][ch0 ^ 4] = make_float4(cp[4], cp[5], cp[6], cp[7]);
      }
      if (tc == 0)
        seup[tr] = ((eul[0] + eul[1]) + (eul[2] + eul[3]))
                 + ((eul[4] + eul[5]) + (eul[6] + eul[7]));
    }
    __syncthreads();                       // barrier 1
    // ---- finalize ev: 512 threads, pair (2k,2k+1) splits the 16 groups ----
    if (tid < 2 * W) {
      const int j  = tid >> 1;
      const int fj = ((((j >> 2) ^ ((j >> 5) & 7)) << 2) | (j & 3));
      const int g0 = (tid & 1) * 8;
      float s = 0.0f;
      #pragma unroll
      for (int g = 0; g < 8; ++g) s += fpart[g0 + g][fj];
      s = dpp_add_xor1(s);                 // pair-combine (same j)
      if (!(tid & 1)) ev_l[fj] = inv2w * rcpf(s + ephi * euW);
    } else if ((tid >> 6) == 8) {          // wave 8: Seu reduce -> evW
      float s = allred32(seup[tid & 31]);
      if (tid == 512) evW_s = 0.5f * rcpf(ephi * (s + euW));
    }
    __syncthreads();                       // barrier 2
    // ---- row pass: in-register u-update via width-32 allreduce ----
    {
      const float evW = evW_s;
      float4 v0 = *(const float4*)&ev_l[ch0];
      float4 v1 = *(const float4*)&ev_l[ch0 ^ 4];
      float vl[8] = {v0.x, v0.y, v0.z, v0.w, v1.x, v1.y, v1.z, v1.w};
      float rp[8];
      #pragma unroll
      for (int a = 0; a < 5; ++a) {
        float s = 0.0f;
        #pragma unroll
        for (int b = 0; b < 8; ++b)
          s = __builtin_fmaf(Er[a][b], vl[b], s);
        rp[a] = s;
      }
      #pragma unroll
      for (int r = 0; r < 3; ++r) {
        float4 e0 = RDCH(2 + 2 * r), e1 = RDCH(3 + 2 * r);
        rp[5 + r] = e0.x * vl[0] + e0.y * vl[1] + e0.z * vl[2] + e0.w * vl[3]
                  + e1.x * vl[4] + e1.y * vl[5] + e1.z * vl[6] + e1.w * vl[7];
      }
      float sev = ((vl[0] + vl[1]) + (vl[2] + vl[3]))
                + ((vl[4] + vl[5]) + (vl[6] + vl[7]));
      #pragma unroll
      for (int a = 0; a < 8; ++a) rp[a] = allred32(rp[a]);
      sev = allred32(sev);
      const float eAdd = ephi * evW;
      #pragma unroll
      for (int a = 0; a < 8; ++a) eul[a] = inv2w * rcpf(rp[a] + eAdd);
      euW = 0.5f * rcpf(ephi * (sev + evW));
    }
  }

  // ---- finale: per-row argmax + 3-tap window, all in-wave ----
  float vl[8];
  {
    float4 v0 = *(const float4*)&ev_l[ch0];
    float4 v1 = *(const float4*)&ev_l[ch0 ^ 4];
    vl[0] = v0.x; vl[1] = v0.y; vl[2] = v0.z; vl[3] = v0.w;
    vl[4] = v1.x; vl[5] = v1.y; vl[6] = v1.z; vl[7] = v1.w;
  }
  float res_disp = 0.0f, res_occ = 0.0f;
  #pragma unroll
  for (int a = 0; a < 8; ++a) {
    float v[8];
    if (a < 5) {
      #pragma unroll
      for (int b = 0; b < 8; ++b) v[b] = Er[a < 5 ? a : 0][b] * vl[b];
    } else {
      float4 e0 = RDCH(2 + 2 * (a - 5)), e1 = RDCH(3 + 2 * (a - 5));
      v[0] = e0.x * vl[0]; v[1] = e0.y * vl[1];
      v[2] = e0.z * vl[2]; v[3] = e0.w * vl[3];
      v[4] = e1.x * vl[4]; v[5] = e1.y * vl[5];
      v[6] = e1.z * vl[6]; v[7] = e1.w * vl[7];
    }
    float m = v[0]; int mj = tc * 8;
    #pragma unroll
    for (int b = 1; b < 8; ++b) {
      if (v[b] > m) { m = v[b]; mj = tc * 8 + b; }   // strict >: first max
    }
    // pack (value, first-index-wins); values > 0 so float bits order-preserve
    unsigned long long best =
        (((unsigned long long)__float_as_uint(m)) << 32) |
        (unsigned)(65535 - mj);
    #pragma unroll
    for (int off = 16; off > 0; off >>= 1) {
      unsigned long long o = __shfl_xor(best, off, 32);
      if (o > best) best = o;
    }
    const int jm = 65535 - (int)(best & 0xffffffffull);
    const int i  = tr * 8 + a;
    const float us = eul[a] * (2.0f * W);
    float num = 0.0f, den = 0.0f;
    #pragma unroll
    for (int b = 0; b < 8; ++b) {
      int j = tc * 8 + b;
      if (j >= jm - 1 && j <= jm + 1) {
        float w = v[b] * us;
        den += w;
        num += w * fmaxf((float)(i - j), 0.0f);
      }
    }
    den = allred32(den);
    num = allred32(num);
    if (tc == a) {                         // lane a keeps row a's result
      float norm = (den < 0.1f) ? 1.0f : den;
      res_disp = num / norm;
      res_occ  = 1.0f - norm;
    }
  }
  if (tc < 8) {
    const int i = tr * 8 + tc;
    out[(size_t)bid * W + i] = res_disp;
    out[(size_t)nh * W + (size_t)bid * W + i] = res_occ;
  }
  #undef RDCH
}

} // namespace

extern "C" void kernel_launch(void* const* d_in, const int* in_sizes, int n_in,
                              void* d_out, int out_size, void* d_ws, size_t ws_size,
                              hipStream_t stream) {
  (void)n_in; (void)d_ws; (void)ws_size; (void)out_size;
  const float* attn = (const float*)d_in[0];
  const float* phi  = (const float*)d_in[1];
  float* out = (float*)d_out;
  const int nh = in_sizes[0] / (W * W);   // 4*120 = 480 matrices
  sinkhorn_disp_kernel<<<dim3(nh), dim3(1024), 0, stream>>>(attn, phi, out, nh);
}

// Round 6
// 235.378 us; speedup vs baseline: 1.8467x; 1.0020x over previous
//
#include <hip/hip_runtime.h>
#include <cstdint>

namespace {

constexpr int W = 256;
constexpr int ITERS = 10;
constexpr int PSTR = 260;   // fpart row stride (floats)

// R13: the VGPR pin is per-THREAD; per-thread E scales with 65536/nthreads.
// At 512 threads + launch_bounds(512,2) the cap is 256 VGPRs and E/thread
// = 128 floats -> THE WHOLE MATRIX LIVES IN REGISTERS (256 KB = half the
// CU's VGPR file), 2 waves/SIMD TLP retained. E-LDS (and its 5.2M
// bank-conflict BW floor) disappears. Schedule is the proven R12 one:
// rg = 2*wave + lane/32 owns rows [16rg,+16); cg = lane&31 owns cols
// [8cg,+8). Col reduce: xor32 pair-combine -> fpart[8][] (XOR-chunk
// swizzled) -> 512-thread pair-split finalize. Row reduce: in-register
// allred32 butterfly. 2 barriers/iter. evW computed by all threads inside
// the finalize window (seup read is barrier-protected there).
__device__ __forceinline__ float dpp_add_xor1(float x) {
  int y = __builtin_amdgcn_mov_dpp(__float_as_int(x), 0xB1, 0xF, 0xF, true);
  return x + __int_as_float(y);
}
__device__ __forceinline__ float dpp_add_xor2(float x) {
  int y = __builtin_amdgcn_mov_dpp(__float_as_int(x), 0x4E, 0xF, 0xF, true);
  return x + __int_as_float(y);
}
template <int PAT>
__device__ __forceinline__ float swz_add(float x) {
  return x + __int_as_float(__builtin_amdgcn_ds_swizzle(__float_as_int(x), PAT));
}
__device__ __forceinline__ float allred32(float x) {  // sum over 32-lane group
  x = dpp_add_xor1(x);
  x = dpp_add_xor2(x);
  x = swz_add<0x101F>(x);   // xor 4
  x = swz_add<0x201F>(x);   // xor 8
  x = swz_add<0x401F>(x);   // xor 16
  return x;
}
__device__ __forceinline__ float rcpf(float x) {
  float r;
  asm("v_rcp_f32 %0, %1" : "=v"(r) : "v"(x));
  return r;
}

__global__ __launch_bounds__(512, 2)
void sinkhorn_disp_kernel(
    const float* __restrict__ attn,
    const float* __restrict__ phi_p,
    float* __restrict__ out,
    int nh)
{
  __shared__ __align__(16) float fpart[8][PSTR];   // 8.3 KB col partials
  __shared__ __align__(16) float ev_l[W];          // swizzled ev
  __shared__ __align__(16) float seup[16];         // per-rg sum(eu)

  const int tid  = threadIdx.x;
  const int lane = tid & 63;
  const int wid  = tid >> 6;                 // wave 0..7
  const int cg   = lane & 31;                // col group: cols [8cg, 8cg+8)
  const int rg   = 2 * wid + (lane >> 5);    // row group: rows [16rg, +16)
  const int bid  = blockIdx.x;

  // swizzled float offset of this thread's first 16B chunk of a 256-f row:
  // chunk c = 2cg+h -> c' = c ^ ((cg>>2)&7); second chunk = ch0 ^ (4 floats)
  const int ch0 = 4 * ((2 * cg) ^ ((cg >> 2) & 7));

  const float ephi = __int_as_float(
      __builtin_amdgcn_readfirstlane(__float_as_int(__expf(phi_p[0]))));
  const float inv2w = 1.0f / (2.0f * W);

  // ---- load + exp: ALL 16 rows -> registers ----
  float Er[16][8];
  {
    const float* src = attn + (size_t)bid * (W * W)
                     + (size_t)(rg * 16) * W + cg * 8;
    #pragma unroll
    for (int r = 0; r < 16; ++r) {
      float4 x0 = *(const float4*)(src + r * W);
      float4 x1 = *(const float4*)(src + r * W + 4);
      Er[r][0] = __expf(x0.x); Er[r][1] = __expf(x0.y);
      Er[r][2] = __expf(x0.z); Er[r][3] = __expf(x0.w);
      Er[r][4] = __expf(x1.x); Er[r][5] = __expf(x1.y);
      Er[r][6] = __expf(x1.z); Er[r][7] = __expf(x1.w);
    }
  }

  float eul[16];
  #pragma unroll
  for (int r = 0; r < 16; ++r) eul[r] = 1.0f;   // u0 = 0 -> eu = 1
  float euW  = 1.0f;
  float evWk = 0.0f;

  for (int it = 0; it < ITERS; ++it) {
    // ---- L3/L2 prefetch of matrix bid+256 (same XCD), iters 2..9 ----
    if (it >= 2 && bid + 256 < nh) {
      const float* pf = attn + (size_t)(bid + 256) * (W * W)
                      + ((size_t)(it - 2) * 512 + tid) * 16;   // 64B lines
      float x = *pf;
      asm volatile("" :: "v"(x));            // keep the load alive
    }
    // ---- col pass: cp[b] = sum_r E[16rg+r][8cg+b] * eu[16rg+r] ----
    {
      float cp[8];
      #pragma unroll
      for (int b = 0; b < 8; ++b) cp[b] = 0.0f;
      #pragma unroll
      for (int r = 0; r < 16; ++r) {
        float u = eul[r];
        #pragma unroll
        for (int b = 0; b < 8; ++b)
          cp[b] = __builtin_fmaf(Er[r][b], u, cp[b]);
      }
      // combine rg-parity pair (lane <-> lane^32: same cg, rg 2w/2w+1)
      #pragma unroll
      for (int b = 0; b < 8; ++b) cp[b] += __shfl_xor(cp[b], 32, 64);
      if (lane < 32) {   // conflict-free b128 writes (chunk XOR swizzle)
        *(float4*)&fpart[wid][ch0    ] = make_float4(cp[0], cp[1], cp[2], cp[3]);
        *(float4*)&fpart[wid][ch0 ^ 4] = make_float4(cp[4], cp[5], cp[6], cp[7]);
      }
      if ((lane & 31) == 0) {
        float s = (((eul[0] + eul[1]) + (eul[2] + eul[3]))
                 + ((eul[4] + eul[5]) + (eul[6] + eul[7])))
                + (((eul[8] + eul[9]) + (eul[10] + eul[11]))
                 + ((eul[12] + eul[13]) + (eul[14] + eul[15])));
        seup[rg] = s;
      }
    }
    __syncthreads();                       // barrier 1
    // ---- finalize ev: 512 threads, pair (2k,2k+1) splits the 8 groups ----
    {
      const int j  = tid >> 1;
      const int fj = ((((j >> 2) ^ ((j >> 5) & 7)) << 2) | (j & 3));
      const int g0 = (tid & 1) * 4;
      float s = (fpart[g0][fj] + fpart[g0 + 1][fj])
              + (fpart[g0 + 2][fj] + fpart[g0 + 3][fj]);
      s = dpp_add_xor1(s);                 // pair-combine (same j)
      if (!(tid & 1)) ev_l[fj] = inv2w * rcpf(s + ephi * euW);
      // every thread: evW from seup (read is safe only inside this window)
      float4 s0 = *(const float4*)&seup[0];
      float4 s1 = *(const float4*)&seup[4];
      float4 s2 = *(const float4*)&seup[8];
      float4 s3 = *(const float4*)&seup[12];
      float Seu = ((((s0.x + s0.y) + (s0.z + s0.w))
                  + ((s1.x + s1.y) + (s1.z + s1.w)))
                 + (((s2.x + s2.y) + (s2.z + s2.w))
                  + ((s3.x + s3.y) + (s3.z + s3.w))));
      evWk = 0.5f * rcpf(ephi * (Seu + euW));
    }
    __syncthreads();                       // barrier 2
    // ---- row pass: in-register u-update via width-32 allreduce ----
    {
      float4 v0 = *(const float4*)&ev_l[ch0];
      float4 v1 = *(const float4*)&ev_l[ch0 ^ 4];
      float vl[8] = {v0.x, v0.y, v0.z, v0.w, v1.x, v1.y, v1.z, v1.w};
      float rp[16];
      #pragma unroll
      for (int r = 0; r < 16; ++r) {
        float s = 0.0f;
        #pragma unroll
        for (int b = 0; b < 8; ++b)
          s = __builtin_fmaf(Er[r][b], vl[b], s);
        rp[r] = s;
      }
      float sev = ((vl[0] + vl[1]) + (vl[2] + vl[3]))
                + ((vl[4] + vl[5]) + (vl[6] + vl[7]));
      #pragma unroll
      for (int r = 0; r < 16; ++r) rp[r] = allred32(rp[r]);
      sev = allred32(sev);
      const float eAdd = ephi * evWk;
      #pragma unroll
      for (int r = 0; r < 16; ++r) eul[r] = inv2w * rcpf(rp[r] + eAdd);
      euW = 0.5f * rcpf(ephi * (sev + evWk));
    }
  }

  // ---- finale: per-row argmax + 3-tap window, all in-half-wave ----
  float vl[8];
  {
    float4 v0 = *(const float4*)&ev_l[ch0];
    float4 v1 = *(const float4*)&ev_l[ch0 ^ 4];
    vl[0] = v0.x; vl[1] = v0.y; vl[2] = v0.z; vl[3] = v0.w;
    vl[4] = v1.x; vl[5] = v1.y; vl[6] = v1.z; vl[7] = v1.w;
  }
  float res_disp = 0.0f, res_occ = 0.0f;
  #pragma unroll
  for (int r = 0; r < 16; ++r) {
    float v[8];
    #pragma unroll
    for (int b = 0; b < 8; ++b) v[b] = Er[r][b] * vl[b];
    float m = v[0]; int mj = cg * 8;
    #pragma unroll
    for (int b = 1; b < 8; ++b) {
      if (v[b] > m) { m = v[b]; mj = cg * 8 + b; }   // strict >: first max
    }
    // pack (value, first-index-wins); values > 0 so float bits order-preserve
    unsigned long long best =
        (((unsigned long long)__float_as_uint(m)) << 32) |
        (unsigned)(65535 - mj);
    #pragma unroll
    for (int off = 16; off > 0; off >>= 1) {
      unsigned long long o = __shfl_xor(best, off, 32);
      if (o > best) best = o;
    }
    const int jm = 65535 - (int)(best & 0xffffffffull);
    const int i  = rg * 16 + r;
    const float us = eul[r] * (2.0f * W);
    float num = 0.0f, den = 0.0f;
    #pragma unroll
    for (int b = 0; b < 8; ++b) {
      int j = cg * 8 + b;
      if (j >= jm - 1 && j <= jm + 1) {
        float wv = v[b] * us;
        den += wv;
        num += wv * fmaxf((float)(i - j), 0.0f);
      }
    }
    den = allred32(den);
    num = allred32(num);
    if (cg == r) {                         // lane r of the half-wave keeps row r
      float norm = (den < 0.1f) ? 1.0f : den;
      res_disp = num / norm;
      res_occ  = 1.0f - norm;
    }
  }
  if (cg < 16) {
    const int i = rg * 16 + cg;
    out[(size_t)bid * W + i] = res_disp;
    out[(size_t)nh * W + (size_t)bid * W + i] = res_occ;
  }
}

} // namespace

extern "C" void kernel_launch(void* const* d_in, const int* in_sizes, int n_in,
                              void* d_out, int out_size, void* d_ws, size_t ws_size,
                              hipStream_t stream) {
  (void)n_in; (void)d_ws; (void)ws_size; (void)out_size;
  const float* attn = (const float*)d_in[0];
  const float* phi  = (const float*)d_in[1];
  float* out = (float*)d_out;
  const int nh = in_sizes[0] / (W * W);   // 4*120 = 480 matrices
  sinkhorn_disp_kernel<<<dim3(nh), dim3(512), 0, stream>>>(attn, phi, out, nh);
}

// Round 7
// 226.436 us; speedup vs baseline: 1.9196x; 1.0395x over previous
//
#include <hip/hip_runtime.h>
#include <cstdint>

namespace {

constexpr int W = 256;
constexpr int ITERS = 10;
constexpr int PSTR = 260;   // fpart row stride (floats)

// R14 = R13 + three changes:
//  (1) amdgpu_waves_per_eu(2,2): R13's VGPR_Count=96 + zero scratch traffic
//      proves the compiler parked Er in AGPRs (unified file) and shuttles
//      them with v_accvgpr_read/write (~256 VALU moves/iter, 2x the FMA
//      work -- explains why killing 5M LDS-conflict cycles gained nothing).
//      Pinning exactly 2 waves/EU gives a 256-reg budget so Er lives in
//      arch VGPRs. Runtime occupancy unchanged (already 2 waves/SIMD).
//  (2) allred32 via 4 DPP adds (xor1, xor2, half-mirror=xor7, mirror=xor15)
//      + one ds_swizzle (xor16): row-reduce DS ops 48 -> 16 per thread/iter.
//  (3) prefetch pipelined: issue at iter top, consume at iter bottom
//      (R13 consumed immediately -> ~900-cycle HBM stall inside each iter).
template <int CTRL>
__device__ __forceinline__ float dpp_add(float x) {
  int y = __builtin_amdgcn_mov_dpp(__float_as_int(x), CTRL, 0xF, 0xF, true);
  return x + __int_as_float(y);
}
template <int PAT>
__device__ __forceinline__ float swz_add(float x) {
  return x + __int_as_float(__builtin_amdgcn_ds_swizzle(__float_as_int(x), PAT));
}
__device__ __forceinline__ float allred32(float x) {  // sum over 32-lane group
  x = dpp_add<0xB1>(x);    // quad_perm xor1
  x = dpp_add<0x4E>(x);    // quad_perm xor2
  x = dpp_add<0x141>(x);   // row_half_mirror = xor7 (span now 0..7)
  x = dpp_add<0x140>(x);   // row_mirror = xor15 (span now 0..15)
  x = swz_add<0x401F>(x);  // xor16 (span 0..31)
  return x;
}
__device__ __forceinline__ float rcpf(float x) {
  float r;
  asm("v_rcp_f32 %0, %1" : "=v"(r) : "v"(x));
  return r;
}

__global__ __launch_bounds__(512)
__attribute__((amdgpu_waves_per_eu(2, 2)))
void sinkhorn_disp_kernel(
    const float* __restrict__ attn,
    const float* __restrict__ phi_p,
    float* __restrict__ out,
    int nh)
{
  __shared__ __align__(16) float fpart[8][PSTR];   // 8.3 KB col partials
  __shared__ __align__(16) float ev_l[W];          // swizzled ev
  __shared__ __align__(16) float seup[16];         // per-rg sum(eu)

  const int tid  = threadIdx.x;
  const int lane = tid & 63;
  const int wid  = tid >> 6;                 // wave 0..7
  const int cg   = lane & 31;                // col group: cols [8cg, 8cg+8)
  const int rg   = 2 * wid + (lane >> 5);    // row group: rows [16rg, +16)
  const int bid  = blockIdx.x;

  // swizzled float offset of this thread's first 16B chunk of a 256-f row:
  // chunk c = 2cg+h -> c' = c ^ ((cg>>2)&7); second chunk = ch0 ^ (4 floats)
  const int ch0 = 4 * ((2 * cg) ^ ((cg >> 2) & 7));

  const float ephi = __int_as_float(
      __builtin_amdgcn_readfirstlane(__float_as_int(__expf(phi_p[0]))));
  const float inv2w = 1.0f / (2.0f * W);

  // ---- load + exp: ALL 16 rows -> registers ----
  float Er[16][8];
  {
    const float* src = attn + (size_t)bid * (W * W)
                     + (size_t)(rg * 16) * W + cg * 8;
    #pragma unroll
    for (int r = 0; r < 16; ++r) {
      float4 x0 = *(const float4*)(src + r * W);
      float4 x1 = *(const float4*)(src + r * W + 4);
      Er[r][0] = __expf(x0.x); Er[r][1] = __expf(x0.y);
      Er[r][2] = __expf(x0.z); Er[r][3] = __expf(x0.w);
      Er[r][4] = __expf(x1.x); Er[r][5] = __expf(x1.y);
      Er[r][6] = __expf(x1.z); Er[r][7] = __expf(x1.w);
    }
  }

  float eul[16];
  #pragma unroll
  for (int r = 0; r < 16; ++r) eul[r] = 1.0f;   // u0 = 0 -> eu = 1
  float euW  = 1.0f;
  float evWk = 0.0f;

  const bool  do_pf = (bid + 256 < nh);
  const float* pfp  = attn + (size_t)(bid + 256) * (W * W) + (size_t)tid * 16;
  float pfv = 0.0f;

  for (int it = 0; it < ITERS; ++it) {
    // ---- L3/L2 prefetch of matrix bid+256: issue now, consume at iter end
    if (do_pf && it < 8)
      pfv = pfp[(size_t)it * (512 * 16)];        // 1 float per 64B line
    // ---- col pass: cp[b] = sum_r E[16rg+r][8cg+b] * eu[16rg+r] ----
    {
      float cp[8];
      #pragma unroll
      for (int b = 0; b < 8; ++b) cp[b] = 0.0f;
      #pragma unroll
      for (int r = 0; r < 16; ++r) {
        float u = eul[r];
        #pragma unroll
        for (int b = 0; b < 8; ++b)
          cp[b] = __builtin_fmaf(Er[r][b], u, cp[b]);
      }
      // combine rg-parity pair (lane <-> lane^32: same cg, rg 2w/2w+1)
      #pragma unroll
      for (int b = 0; b < 8; ++b) cp[b] += __shfl_xor(cp[b], 32, 64);
      if (lane < 32) {   // conflict-free b128 writes (chunk XOR swizzle)
        *(float4*)&fpart[wid][ch0    ] = make_float4(cp[0], cp[1], cp[2], cp[3]);
        *(float4*)&fpart[wid][ch0 ^ 4] = make_float4(cp[4], cp[5], cp[6], cp[7]);
      }
      if ((lane & 31) == 0) {
        float s = (((eul[0] + eul[1]) + (eul[2] + eul[3]))
                 + ((eul[4] + eul[5]) + (eul[6] + eul[7])))
                + (((eul[8] + eul[9]) + (eul[10] + eul[11]))
                 + ((eul[12] + eul[13]) + (eul[14] + eul[15])));
        seup[rg] = s;
      }
    }
    __syncthreads();                       // barrier 1
    // ---- finalize ev: 512 threads, pair (2k,2k+1) splits the 8 groups ----
    {
      const int j  = tid >> 1;
      const int fj = ((((j >> 2) ^ ((j >> 5) & 7)) << 2) | (j & 3));
      const int g0 = (tid & 1) * 4;
      float s = (fpart[g0][fj] + fpart[g0 + 1][fj])
              + (fpart[g0 + 2][fj] + fpart[g0 + 3][fj]);
      s = dpp_add<0xB1>(s);                // pair-combine (same j)
      if (!(tid & 1)) ev_l[fj] = inv2w * rcpf(s + ephi * euW);
      // every thread: evW from seup (read is safe only inside this window)
      float4 s0 = *(const float4*)&seup[0];
      float4 s1 = *(const float4*)&seup[4];
      float4 s2 = *(const float4*)&seup[8];
      float4 s3 = *(const float4*)&seup[12];
      float Seu = ((((s0.x + s0.y) + (s0.z + s0.w))
                  + ((s1.x + s1.y) + (s1.z + s1.w)))
                 + (((s2.x + s2.y) + (s2.z + s2.w))
                  + ((s3.x + s3.y) + (s3.z + s3.w))));
      evWk = 0.5f * rcpf(ephi * (Seu + euW));
    }
    __syncthreads();                       // barrier 2
    // ---- row pass: in-register u-update via width-32 allreduce ----
    {
      float4 v0 = *(const float4*)&ev_l[ch0];
      float4 v1 = *(const float4*)&ev_l[ch0 ^ 4];
      float vl[8] = {v0.x, v0.y, v0.z, v0.w, v1.x, v1.y, v1.z, v1.w};
      float rp[16];
      #pragma unroll
      for (int r = 0; r < 16; ++r) {
        float s = 0.0f;
        #pragma unroll
        for (int b = 0; b < 8; ++b)
          s = __builtin_fmaf(Er[r][b], vl[b], s);
        rp[r] = s;
      }
      float sev = ((vl[0] + vl[1]) + (vl[2] + vl[3]))
                + ((vl[4] + vl[5]) + (vl[6] + vl[7]));
      #pragma unroll
      for (int r = 0; r < 16; ++r) rp[r] = allred32(rp[r]);
      sev = allred32(sev);
      const float eAdd = ephi * evWk;
      #pragma unroll
      for (int r = 0; r < 16; ++r) eul[r] = inv2w * rcpf(rp[r] + eAdd);
      euW = 0.5f * rcpf(ephi * (sev + evWk));
    }
    // ---- consume the prefetch issued at iter top (latency fully hidden) --
    if (do_pf && it < 8) asm volatile("" :: "v"(pfv));
  }

  // ---- finale: per-row argmax + 3-tap window, all in-half-wave ----
  float vl[8];
  {
    float4 v0 = *(const float4*)&ev_l[ch0];
    float4 v1 = *(const float4*)&ev_l[ch0 ^ 4];
    vl[0] = v0.x; vl[1] = v0.y; vl[2] = v0.z; vl[3] = v0.w;
    vl[4] = v1.x; vl[5] = v1.y; vl[6] = v1.z; vl[7] = v1.w;
  }
  float res_disp = 0.0f, res_occ = 0.0f;
  #pragma unroll
  for (int r = 0; r < 16; ++r) {
    float v[8];
    #pragma unroll
    for (int b = 0; b < 8; ++b) v[b] = Er[r][b] * vl[b];
    float m = v[0]; int mj = cg * 8;
    #pragma unroll
    for (int b = 1; b < 8; ++b) {
      if (v[b] > m) { m = v[b]; mj = cg * 8 + b; }   // strict >: first max
    }
    // pack (value, first-index-wins); values > 0 so float bits order-preserve
    unsigned long long best =
        (((unsigned long long)__float_as_uint(m)) << 32) |
        (unsigned)(65535 - mj);
    #pragma unroll
    for (int off = 16; off > 0; off >>= 1) {
      unsigned long long o = __shfl_xor(best, off, 32);
      if (o > best) best = o;
    }
    const int jm = 65535 - (int)(best & 0xffffffffull);
    const int i  = rg * 16 + r;
    const float us = eul[r] * (2.0f * W);
    float num = 0.0f, den = 0.0f;
    #pragma unroll
    for (int b = 0; b < 8; ++b) {
      int j = cg * 8 + b;
      if (j >= jm - 1 && j <= jm + 1) {
        float wv = v[b] * us;
        den += wv;
        num += wv * fmaxf((float)(i - j), 0.0f);
      }
    }
    den = allred32(den);
    num = allred32(num);
    if (cg == r) {                         // lane r of the half-wave keeps row r
      float norm = (den < 0.1f) ? 1.0f : den;
      res_disp = num / norm;
      res_occ  = 1.0f - norm;
    }
  }
  if (cg < 16) {
    const int i = rg * 16 + cg;
    out[(size_t)bid * W + i] = res_disp;
    out[(size_t)nh * W + (size_t)bid * W + i] = res_occ;
  }
}

} // namespace

extern "C" void kernel_launch(void* const* d_in, const int* in_sizes, int n_in,
                              void* d_out, int out_size, void* d_ws, size_t ws_size,
                              hipStream_t stream) {
  (void)n_in; (void)d_ws; (void)ws_size; (void)out_size;
  const float* attn = (const float*)d_in[0];
  const float* phi  = (const float*)d_in[1];
  float* out = (float*)d_out;
  const int nh = in_sizes[0] / (W * W);   // 4*120 = 480 matrices
  sinkhorn_disp_kernel<<<dim3(nh), dim3(512), 0, stream>>>(attn, phi, out, nh);
}